// Round 6
// baseline (144.216 us; speedup 1.0000x reference)
//
#include <hip/hip_runtime.h>

#define NN  50000
#define DEG 32
#define DF  128
#define DO  256
#define FEAT4 (NN * DF / 4)   // 1,600,000 float4 groups

typedef __bf16 bf16x8 __attribute__((ext_vector_type(8)));
typedef float  f32x4  __attribute__((ext_vector_type(4)));
typedef float  f32x2  __attribute__((ext_vector_type(2)));
typedef unsigned short u16x8 __attribute__((ext_vector_type(8)));

#if defined(__has_builtin)
#if __has_builtin(__builtin_amdgcn_cvt_pk_f32_fp8) && __has_builtin(__builtin_amdgcn_cvt_pk_fp8_f32)
#define HW_FP8 1
#endif
#endif
#ifndef HW_FP8
#define HW_FP8 0
#endif

__device__ __forceinline__ unsigned short f2bf(float f) {
    unsigned u = __float_as_uint(f);
    u += 0x7FFF + ((u >> 16) & 1);     // round-to-nearest-even
    return (unsigned short)(u >> 16);
}

#if !HW_FP8
__device__ __forceinline__ unsigned enc1_fp8(float f) {
    unsigned u = __float_as_uint(f);
    unsigned s = (u >> 31) << 7;
    float a = fabsf(f);
    if (!(a > 0.f)) return s;
    if (a >= 448.f) return s | 0x7E;
    u = __float_as_uint(a);
    int e = (int)((u >> 23) & 255) - 127;
    if (e < -6) {
        unsigned m = (unsigned)(a * 512.f + 0.5f);
        if (m >= 8) return s | 0x08;
        return s | m;
    }
    unsigned mant = (u >> 20) & 7;
    unsigned rnd  = ((u >> 19) & 1) & (((u & 0x7FFFF) != 0) | ((u >> 20) & 1));
    unsigned enc  = ((unsigned)(e + 7) << 3) | mant;
    return s | (enc + rnd);
}
__device__ __forceinline__ float dec1_fp8(unsigned b) {
    unsigned s = (b >> 7) & 1, e = (b >> 3) & 15, m = b & 7;
    float v = (e == 0) ? (float)m * 0.001953125f
                       : __uint_as_float(((e - 7 + 127) << 23) | (m << 20));
    return s ? -v : v;
}
#endif

__device__ __forceinline__ unsigned enc4_fp8(float4 v) {
#if HW_FP8
    int pk = 0;
    pk = __builtin_amdgcn_cvt_pk_fp8_f32(v.x, v.y, pk, false);
    pk = __builtin_amdgcn_cvt_pk_fp8_f32(v.z, v.w, pk, true);
    return (unsigned)pk;
#else
    return enc1_fp8(v.x) | (enc1_fp8(v.y) << 8) | (enc1_fp8(v.z) << 16) | (enc1_fp8(v.w) << 24);
#endif
}

// ---------------------------------------------------------------------------
// Convert: feat fp32 -> {fp8 e4m3 gather table, bf16 GEMM copy};
//          W fp32 [K][N] -> Wt bf16 [N][K].
// ---------------------------------------------------------------------------
__global__ __launch_bounds__(256) void convert_kernel(
    const float* __restrict__ feat, const float* __restrict__ W,
    unsigned* __restrict__ feat8, unsigned short* __restrict__ featb,
    unsigned short* __restrict__ Wt)
{
    const int gid = blockIdx.x * 256 + threadIdx.x;
    if (gid < FEAT4) {
        const float4 v = ((const float4*)feat)[gid];
        feat8[gid] = enc4_fp8(v);
        ushort4 o;
        o.x = f2bf(v.x); o.y = f2bf(v.y); o.z = f2bf(v.z); o.w = f2bf(v.w);
        ((ushort4*)featb)[gid] = o;
    } else {
        const int t = gid - FEAT4;
        if (t < DO * DO) {
            const int n = t >> 8, k = t & 255;
            Wt[n * DO + k] = f2bf(W[k * DO + n]);   // write coalesced along k
        }
    }
}

// ---------------------------------------------------------------------------
// Aggregation from the fp8 table (at its ~18 us fill floor: 8 XCDs x 6.4 MB
// compulsory + edges). 16 nodes/block, 16 lanes/node x 8 B, fp32 accumulate,
// bf16 out.
// ---------------------------------------------------------------------------
__global__ __launch_bounds__(256) void agg_kernel(
    const unsigned* __restrict__ feat8,
    const int*      __restrict__ edges,
    unsigned short* __restrict__ aggb)
{
    const int node = blockIdx.x * 16 + (threadIdx.x >> 4);
    const int l    = threadIdx.x & 15;
    const int* e   = edges + node * DEG;

    float a[8] = {0.f, 0.f, 0.f, 0.f, 0.f, 0.f, 0.f, 0.f};
    #pragma unroll
    for (int d = 0; d < DEG; ++d) {
        const int idx = e[d];
        const uint2 pk = *(const uint2*)(feat8 + (size_t)idx * (DF / 4) + l * 2);
#if HW_FP8
        const f32x2 v0 = __builtin_amdgcn_cvt_pk_f32_fp8((int)pk.x, false);
        const f32x2 v1 = __builtin_amdgcn_cvt_pk_f32_fp8((int)pk.x, true);
        const f32x2 v2 = __builtin_amdgcn_cvt_pk_f32_fp8((int)pk.y, false);
        const f32x2 v3 = __builtin_amdgcn_cvt_pk_f32_fp8((int)pk.y, true);
        a[0] += v0[0]; a[1] += v0[1]; a[2] += v1[0]; a[3] += v1[1];
        a[4] += v2[0]; a[5] += v2[1]; a[6] += v3[0]; a[7] += v3[1];
#else
        #pragma unroll
        for (int j = 0; j < 4; ++j) a[j]     += dec1_fp8((pk.x >> (8 * j)) & 255);
        #pragma unroll
        for (int j = 0; j < 4; ++j) a[4 + j] += dec1_fp8((pk.y >> (8 * j)) & 255);
#endif
    }

    const float s = 1.0f / (float)DEG;
    u16x8 o;
    #pragma unroll
    for (int j = 0; j < 8; ++j) o[j] = f2bf(a[j] * s);
    *(u16x8*)(aggb + (size_t)node * DF + l * 8) = o;
}

// ---------------------------------------------------------------------------
// LDS-free, barrier-free GEMM: out = relu([featb | aggb] @ Wt^T).
// One block per 64 nodes, BN = 256. With BN = D_OUT each A-row is consumed
// by exactly ONE block, so LDS staging would buy zero reuse — MFMA A/B
// fragments are loaded straight from global (bf16, 16 B/lane; each wave-load
// touches 16 rows x 64 B contiguous). Wt (128 KB) is L2-resident.
// K-loop fully unrolled; per kk the A source switches featb -> aggb at
// compile time (the concat never materializes).
// ---------------------------------------------------------------------------
#define BM 64

__global__ __launch_bounds__(256) void gemm_kernel(
    const unsigned short* __restrict__ featb,
    const unsigned short* __restrict__ aggb,
    const unsigned short* __restrict__ Wt,
    float*                __restrict__ out)
{
    const int tid  = threadIdx.x;
    const int m0   = blockIdx.x * BM;
    const int wave = tid >> 6, lane = tid & 63;
    const int quad = lane >> 4, lr = lane & 15;
    const int wn   = wave * 64;          // each wave owns 64 output cols

    f32x4 acc[4][4] = {};

    #pragma unroll
    for (int kk = 0; kk < 256; kk += 32) {
        const unsigned short* Asrc = (kk < DF) ? (featb + kk) : (aggb + (kk - DF));
        bf16x8 af[4], bfr[4];
        #pragma unroll
        for (int i = 0; i < 4; ++i) {
            int row = m0 + i * 16 + lr;
            if (row >= NN) row = NN - 1;            // clamp; stores guarded
            af[i]  = *(const bf16x8*)(Asrc + (size_t)row * DF + quad * 8);
            bfr[i] = *(const bf16x8*)(Wt + (size_t)(wn + i * 16 + lr) * DO + kk + quad * 8);
        }
        #pragma unroll
        for (int mi = 0; mi < 4; ++mi)
            #pragma unroll
            for (int ni = 0; ni < 4; ++ni)
                acc[mi][ni] = __builtin_amdgcn_mfma_f32_16x16x32_bf16(
                    af[mi], bfr[ni], acc[mi][ni], 0, 0, 0);
    }

    // epilogue: relu + guarded store. C/D: col=lane&15, row=quad*4+reg.
    #pragma unroll
    for (int mi = 0; mi < 4; ++mi) {
        #pragma unroll
        for (int r = 0; r < 4; ++r) {
            const int row = m0 + mi * 16 + quad * 4 + r;
            if (row < NN) {
                #pragma unroll
                for (int ni = 0; ni < 4; ++ni) {
                    out[(size_t)row * DO + wn + ni * 16 + lr] =
                        fmaxf(acc[mi][ni][r], 0.f);
                }
            }
        }
    }
}

extern "C" void kernel_launch(void* const* d_in, const int* in_sizes, int n_in,
                              void* d_out, int out_size, void* d_ws, size_t ws_size,
                              hipStream_t stream)
{
    const float* feat  = (const float*)d_in[0];
    const int*   edges = (const int*)d_in[1];
    const float* W     = (const float*)d_in[2];
    float*       out   = (float*)d_out;

    unsigned short* aggb  = (unsigned short*)d_ws;                 // 12.8 MB
    unsigned*       feat8 = (unsigned*)(aggb + (size_t)NN * DF);   // 6.4 MB
    unsigned short* featb = (unsigned short*)(feat8 + (size_t)NN * DF / 4); // 12.8 MB
    unsigned short* Wt    = featb + (size_t)NN * DF;               // 128 KB

    convert_kernel<<<(FEAT4 + DO * DO + 255) / 256, 256, 0, stream>>>(
        feat, W, feat8, featb, Wt);
    agg_kernel<<<NN / 16, 256, 0, stream>>>(feat8, edges, aggb);
    gemm_kernel<<<(NN + BM - 1) / BM, 256, 0, stream>>>(featb, aggb, Wt, out);
}

// Round 7
// 122.509 us; speedup vs baseline: 1.1772x; 1.1772x over previous
//
#include <hip/hip_runtime.h>

#define NN  50000
#define DEG 32
#define DF  128
#define DO  256
#define FEAT4 (NN * DF / 4)   // 1,600,000 float4 groups

typedef __bf16 bf16x8 __attribute__((ext_vector_type(8)));
typedef float  f32x4  __attribute__((ext_vector_type(4)));
typedef float  f32x2  __attribute__((ext_vector_type(2)));
typedef unsigned short u16x8 __attribute__((ext_vector_type(8)));

#if defined(__has_builtin)
#if __has_builtin(__builtin_amdgcn_cvt_pk_f32_fp8) && __has_builtin(__builtin_amdgcn_cvt_pk_fp8_f32)
#define HW_FP8 1
#endif
#endif
#ifndef HW_FP8
#define HW_FP8 0
#endif

__device__ __forceinline__ unsigned short f2bf(float f) {
    unsigned u = __float_as_uint(f);
    u += 0x7FFF + ((u >> 16) & 1);     // round-to-nearest-even
    return (unsigned short)(u >> 16);
}

#if !HW_FP8
__device__ __forceinline__ unsigned enc1_fp8(float f) {
    unsigned u = __float_as_uint(f);
    unsigned s = (u >> 31) << 7;
    float a = fabsf(f);
    if (!(a > 0.f)) return s;
    if (a >= 448.f) return s | 0x7E;
    u = __float_as_uint(a);
    int e = (int)((u >> 23) & 255) - 127;
    if (e < -6) {
        unsigned m = (unsigned)(a * 512.f + 0.5f);
        if (m >= 8) return s | 0x08;
        return s | m;
    }
    unsigned mant = (u >> 20) & 7;
    unsigned rnd  = ((u >> 19) & 1) & (((u & 0x7FFFF) != 0) | ((u >> 20) & 1));
    unsigned enc  = ((unsigned)(e + 7) << 3) | mant;
    return s | (enc + rnd);
}
__device__ __forceinline__ float dec1_fp8(unsigned b) {
    unsigned s = (b >> 7) & 1, e = (b >> 3) & 15, m = b & 7;
    float v = (e == 0) ? (float)m * 0.001953125f
                       : __uint_as_float(((e - 7 + 127) << 23) | (m << 20));
    return s ? -v : v;
}
#endif

__device__ __forceinline__ unsigned enc4_fp8(float4 v) {
#if HW_FP8
    int pk = 0;
    pk = __builtin_amdgcn_cvt_pk_fp8_f32(v.x, v.y, pk, false);
    pk = __builtin_amdgcn_cvt_pk_fp8_f32(v.z, v.w, pk, true);
    return (unsigned)pk;
#else
    return enc1_fp8(v.x) | (enc1_fp8(v.y) << 8) | (enc1_fp8(v.z) << 16) | (enc1_fp8(v.w) << 24);
#endif
}

// ---------------------------------------------------------------------------
// Convert: feat fp32 -> {fp8 e4m3 gather table, bf16 GEMM copy};
//          W fp32 [K][N] -> Wt bf16 [N][K].
// ---------------------------------------------------------------------------
__global__ __launch_bounds__(256) void convert_kernel(
    const float* __restrict__ feat, const float* __restrict__ W,
    unsigned* __restrict__ feat8, unsigned short* __restrict__ featb,
    unsigned short* __restrict__ Wt)
{
    const int gid = blockIdx.x * 256 + threadIdx.x;
    if (gid < FEAT4) {
        const float4 v = ((const float4*)feat)[gid];
        feat8[gid] = enc4_fp8(v);
        ushort4 o;
        o.x = f2bf(v.x); o.y = f2bf(v.y); o.z = f2bf(v.z); o.w = f2bf(v.w);
        ((ushort4*)featb)[gid] = o;
    } else {
        const int t = gid - FEAT4;
        if (t < DO * DO) {
            const int n = t >> 8, k = t & 255;
            Wt[n * DO + k] = f2bf(W[k * DO + n]);   // write coalesced along k
        }
    }
}

// ---------------------------------------------------------------------------
// Aggregation from the fp8 table (at its ~18 us per-XCD compulsory-fill
// floor). 16 nodes/block, 16 lanes/node x 8 B, fp32 accumulate, bf16 out.
// ---------------------------------------------------------------------------
__global__ __launch_bounds__(256) void agg_kernel(
    const unsigned* __restrict__ feat8,
    const int*      __restrict__ edges,
    unsigned short* __restrict__ aggb)
{
    const int node = blockIdx.x * 16 + (threadIdx.x >> 4);
    const int l    = threadIdx.x & 15;
    const int* e   = edges + node * DEG;

    float a[8] = {0.f, 0.f, 0.f, 0.f, 0.f, 0.f, 0.f, 0.f};
    #pragma unroll
    for (int d = 0; d < DEG; ++d) {
        const int idx = e[d];
        const uint2 pk = *(const uint2*)(feat8 + (size_t)idx * (DF / 4) + l * 2);
#if HW_FP8
        const f32x2 v0 = __builtin_amdgcn_cvt_pk_f32_fp8((int)pk.x, false);
        const f32x2 v1 = __builtin_amdgcn_cvt_pk_f32_fp8((int)pk.x, true);
        const f32x2 v2 = __builtin_amdgcn_cvt_pk_f32_fp8((int)pk.y, false);
        const f32x2 v3 = __builtin_amdgcn_cvt_pk_f32_fp8((int)pk.y, true);
        a[0] += v0[0]; a[1] += v0[1]; a[2] += v1[0]; a[3] += v1[1];
        a[4] += v2[0]; a[5] += v2[1]; a[6] += v3[0]; a[7] += v3[1];
#else
        #pragma unroll
        for (int j = 0; j < 4; ++j) a[j]     += dec1_fp8((pk.x >> (8 * j)) & 255);
        #pragma unroll
        for (int j = 0; j < 4; ++j) a[4 + j] += dec1_fp8((pk.y >> (8 * j)) & 255);
#endif
    }

    const float s = 1.0f / (float)DEG;
    u16x8 o;
    #pragma unroll
    for (int j = 0; j < 8; ++j) o[j] = f2bf(a[j] * s);
    *(u16x8*)(aggb + (size_t)node * DF + l * 8) = o;
}

// ---------------------------------------------------------------------------
// MFMA GEMM — the twice-measured ~40 us R2/R4 structure, unchanged:
// 128x128 block tile, 4 waves 2x2, 16x16x32 bf16 MFMA, K in 4 chunks of 64
// staged through LDS with coalesced float4 reads (this staging is the
// access-pattern transpose; removing it (R6) costs 16 lines/wave-load).
// LDS rows padded to 72 bf16 -> worst 2-way conflicts on ds_read_b128 (free).
// ---------------------------------------------------------------------------
#define BM  128
#define BN  128
#define LDA 72

__global__ __launch_bounds__(256) void gemm_kernel(
    const unsigned short* __restrict__ featb,
    const unsigned short* __restrict__ aggb,
    const unsigned short* __restrict__ Wt,
    float*                __restrict__ out)
{
    __shared__ __align__(16) unsigned short Asw[BM * LDA];
    __shared__ __align__(16) unsigned short Bsw[BN * LDA];

    const int tid  = threadIdx.x;
    const int m0   = blockIdx.x * BM;
    const int c0   = blockIdx.y * BN;
    const int wave = tid >> 6, lane = tid & 63;
    const int quad = lane >> 4, lr = lane & 15;
    const int wm   = (wave & 1) * 64;
    const int wn   = (wave >> 1) * 64;

    const int srow = tid >> 3;
    const int sseg = (tid & 7) * 8;

    f32x4 acc[4][4] = {};

    for (int kc = 0; kc < 4; ++kc) {
        const unsigned short* srcA = (kc < 2) ? (featb + kc * 64)
                                              : (aggb + (kc - 2) * 64);
        const unsigned short* srcB = Wt + kc * 64;

        __syncthreads();
        #pragma unroll
        for (int p = 0; p < 4; ++p) {
            const int r = p * 32 + srow;
            int node = m0 + r;
            if (node >= NN) node = NN - 1;
            const float4 va = *(const float4*)(srcA + (size_t)node * DF + sseg);
            *(float4*)(Asw + r * LDA + sseg) = va;
            const float4 vb = *(const float4*)(srcB + (size_t)(c0 + r) * DO + sseg);
            *(float4*)(Bsw + r * LDA + sseg) = vb;
        }
        __syncthreads();

        #pragma unroll
        for (int kk = 0; kk < 64; kk += 32) {
            bf16x8 af[4], bfr[4];
            #pragma unroll
            for (int i = 0; i < 4; ++i) {
                af[i]  = *(const bf16x8*)(Asw + (wm + i * 16 + lr) * LDA + kk + quad * 8);
                bfr[i] = *(const bf16x8*)(Bsw + (wn + i * 16 + lr) * LDA + kk + quad * 8);
            }
            #pragma unroll
            for (int mi = 0; mi < 4; ++mi)
                #pragma unroll
                for (int ni = 0; ni < 4; ++ni)
                    acc[mi][ni] = __builtin_amdgcn_mfma_f32_16x16x32_bf16(
                        af[mi], bfr[ni], acc[mi][ni], 0, 0, 0);
        }
    }

    #pragma unroll
    for (int mi = 0; mi < 4; ++mi) {
        #pragma unroll
        for (int r = 0; r < 4; ++r) {
            const int row = m0 + wm + mi * 16 + quad * 4 + r;
            if (row < NN) {
                #pragma unroll
                for (int ni = 0; ni < 4; ++ni) {
                    out[(size_t)row * DO + c0 + wn + ni * 16 + lr] =
                        fmaxf(acc[mi][ni][r], 0.f);
                }
            }
        }
    }
}

extern "C" void kernel_launch(void* const* d_in, const int* in_sizes, int n_in,
                              void* d_out, int out_size, void* d_ws, size_t ws_size,
                              hipStream_t stream)
{
    const float* feat  = (const float*)d_in[0];
    const int*   edges = (const int*)d_in[1];
    const float* W     = (const float*)d_in[2];
    float*       out   = (float*)d_out;

    unsigned short* aggb  = (unsigned short*)d_ws;                 // 12.8 MB
    unsigned*       feat8 = (unsigned*)(aggb + (size_t)NN * DF);   // 6.4 MB
    unsigned short* featb = (unsigned short*)(feat8 + (size_t)NN * DF / 4); // 12.8 MB
    unsigned short* Wt    = featb + (size_t)NN * DF;               // 128 KB

    convert_kernel<<<(FEAT4 + DO * DO + 255) / 256, 256, 0, stream>>>(
        feat, W, feat8, featb, Wt);
    agg_kernel<<<NN / 16, 256, 0, stream>>>(feat8, edges, aggb);

    dim3 grid((NN + BM - 1) / BM, DO / BN);
    gemm_kernel<<<grid, 256, 0, stream>>>(featb, aggb, Wt, out);
}